// Round 6
// baseline (1500.114 us; speedup 1.0000x reference)
//
#include <hip/hip_runtime.h>
#include <hip/hip_bf16.h>
#include <math.h>

#define D 64
#define RU 256
#define CHUNK 16

typedef short bf16x8 __attribute__((ext_vector_type(8)));
typedef float f32x4 __attribute__((ext_vector_type(4)));

__device__ __forceinline__ float selu_f(float x) {
    return x > 0.0f ? 1.0507009873554805f * x
                    : 1.7580993408473766f * (__expf(x) - 1.0f);
}

__device__ __forceinline__ short f2bf_rtne(float x) {
    union { float f; unsigned u; } v; v.f = x;
    unsigned r = (v.u + 0x7FFFu + ((v.u >> 16) & 1u)) >> 16;
    return (short)r;
}
__device__ __forceinline__ float bf2f(short s) {
    union { float f; unsigned u; } v; v.u = ((unsigned)(unsigned short)s) << 16;
    return v.f;
}

// Pack 8 floats -> bf16x8 (RTNE) via packed cvt.
__device__ __forceinline__ bf16x8 pack8(const float* v) {
    union { bf16x8 v; unsigned u[4]; } H;
#pragma unroll
    for (int j = 0; j < 4; ++j) {
        float2 p; p.x = v[2 * j]; p.y = v[2 * j + 1];
        __hip_bfloat162 hb = __float22bfloat162_rn(p);
        H.u[j] = *(unsigned*)&hb;
    }
    return H.v;
}

// Split 8 floats into hi/lo bf16x8 (RTNE both).
__device__ __forceinline__ void split_pack8(const float* v, bf16x8* hi, bf16x8* lo) {
    union { bf16x8 v; unsigned u[4]; } H, L;
#pragma unroll
    for (int j = 0; j < 4; ++j) {
        float2 p; p.x = v[2 * j]; p.y = v[2 * j + 1];
        __hip_bfloat162 hb = __float22bfloat162_rn(p);
        unsigned hu = *(unsigned*)&hb;
        H.u[j] = hu;
        union { unsigned u; float f; } e, o;
        e.u = hu << 16;
        o.u = hu & 0xffff0000u;
        float2 q; q.x = p.x - e.f; q.y = p.y - o.f;
        __hip_bfloat162 lb = __float22bfloat162_rn(q);
        L.u[j] = *(unsigned*)&lb;
    }
    *hi = H.v; *lo = L.v;
}

// ---------------- CSR setup (once per launch) ----------------

__global__ __launch_bounds__(256) void hist_kernel(
    const int* __restrict__ keys, int* __restrict__ counts, int n)
{
    for (int e = blockIdx.x * blockDim.x + threadIdx.x; e < n;
         e += gridDim.x * blockDim.x)
        atomicAdd(&counts[keys[e]], 1);
}

__global__ __launch_bounds__(1024) void scan_kernel(
    const int* __restrict__ counts, int* __restrict__ row_ptr,
    int* __restrict__ cursor, int n)
{
    __shared__ int wsum[16];
    __shared__ int woff[16];
    __shared__ int s_total;
    __shared__ int s_carry;
    const int tid = threadIdx.x, wave = tid >> 6, lane = tid & 63;
    if (tid == 0) s_carry = 0;
    __syncthreads();
    for (int base = 0; base < n; base += 1024) {
        const int i = base + tid;
        const int x = (i < n) ? counts[i] : 0;
        int v = x;
#pragma unroll
        for (int off = 1; off < 64; off <<= 1) {
            int t = __shfl_up(v, off, 64);
            if (lane >= off) v += t;
        }
        if (lane == 63) wsum[wave] = v;
        __syncthreads();
        if (wave == 0) {
            int s = (lane < 16) ? wsum[lane] : 0;
#pragma unroll
            for (int off = 1; off < 16; off <<= 1) {
                int t = __shfl_up(s, off, 64);
                if (lane >= off) s += t;
            }
            if (lane < 16) woff[lane] = s - wsum[lane];
            if (lane == 15) s_total = s;
        }
        __syncthreads();
        const int carry = s_carry;
        const int excl = carry + woff[wave] + (v - x);
        if (i < n) { row_ptr[i] = excl; cursor[i] = excl; }
        __syncthreads();
        if (tid == 0) s_carry += s_total;
        __syncthreads();
    }
    if (tid == 0) row_ptr[n] = s_carry;
}

__global__ __launch_bounds__(256) void scatter_kernel(
    const int* __restrict__ first, const int* __restrict__ second,
    int* __restrict__ cursor, int* __restrict__ sfirst, int n_edges)
{
    for (int e = blockIdx.x * blockDim.x + threadIdx.x; e < n_edges;
         e += gridDim.x * blockDim.x) {
        const int pos = atomicAdd(&cursor[second[e]], 1);
        sfirst[pos] = first[e];
    }
}

// ---------------- P via MFMA (split-bf16, fp32-equivalent) ----------------
// P = state @ W_msg[0:64,:]
__global__ __launch_bounds__(256) void p_mfma_kernel(
    const float* __restrict__ state, const float* __restrict__ W_msg,
    float* __restrict__ P, int n_links)
{
    const int tid = threadIdx.x;
    const int wave = tid >> 6;
    const int lane = tid & 63;
    const int m = lane & 15;
    const int qd = lane >> 4;

    bf16x8 Bh[2][4], Bl[2][4];
#pragma unroll
    for (int ks = 0; ks < 2; ++ks)
#pragma unroll
        for (int jt = 0; jt < 4; ++jt) {
            const int nn = jt * 16 + m;
#pragma unroll
            for (int i = 0; i < 8; ++i) {
                const int kk = ks * 32 + qd * 8 + i;
                const float w = W_msg[kk * 64 + nn];
                const short hi = f2bf_rtne(w);
                Bh[ks][jt][i] = hi;
                Bl[ks][jt][i] = f2bf_rtne(w - bf2f(hi));
            }
        }

    const int ngroups = (n_links + 63) >> 6;
    for (int g = blockIdx.x; g < ngroups; g += gridDim.x) {
        const int base = g * 64 + wave * 16;
        const int l = base + m;
        const bool lv = (l < n_links);
        float xv[16];
        if (lv) {
            const float4* Sr = (const float4*)(state + (size_t)l * D);
            *(float4*)&xv[0]  = Sr[qd * 2];
            *(float4*)&xv[4]  = Sr[qd * 2 + 1];
            *(float4*)&xv[8]  = Sr[8 + qd * 2];
            *(float4*)&xv[12] = Sr[9 + qd * 2];
        } else {
#pragma unroll
            for (int i = 0; i < 16; ++i) xv[i] = 0.0f;
        }
        bf16x8 Ah[2], Al[2];
        split_pack8(&xv[0], &Ah[0], &Al[0]);
        split_pack8(&xv[8], &Ah[1], &Al[1]);
        f32x4 accP[4];
#pragma unroll
        for (int jt = 0; jt < 4; ++jt) {
            accP[jt] = (f32x4){0.f, 0.f, 0.f, 0.f};
#pragma unroll
            for (int ks = 0; ks < 2; ++ks) {
                accP[jt] = __builtin_amdgcn_mfma_f32_16x16x32_bf16(Ah[ks], Bh[ks][jt], accP[jt], 0, 0, 0);
                accP[jt] = __builtin_amdgcn_mfma_f32_16x16x32_bf16(Ah[ks], Bl[ks][jt], accP[jt], 0, 0, 0);
                accP[jt] = __builtin_amdgcn_mfma_f32_16x16x32_bf16(Al[ks], Bh[ks][jt], accP[jt], 0, 0, 0);
            }
        }
#pragma unroll
        for (int r = 0; r < 4; ++r) {
            const int lr = base + qd * 4 + r;
            if (lr < n_links) {
#pragma unroll
                for (int jt = 0; jt < 4; ++jt)
                    P[(size_t)lr * D + jt * 16 + m] = accP[jt][r];
            }
        }
    }
}

// ---------------- link-centric fused edge kernel ----------------
// Wave owns CHUNK=16 consecutive links. Phase 1: compute Q-tile =
// state[l0:l0+16] @ W_msg_bot + b_msg via split-MFMA, stash in LDS
// (C-layout -> A-layout transform). Phase 2: per link, gather P[fi],
// selu, plain-bf16 A x split-bf16 W_gcn MFMA, relu, register row-sum,
// one plain store of S[l]. No atomics, no barriers.
#define QSTRIDE 68
__global__ __launch_bounds__(256) void edge_link_kernel(
    const float* state, const float* __restrict__ P,
    const int* __restrict__ sfirst, const int* __restrict__ row_ptr,
    const float* __restrict__ b_msg, const float* __restrict__ W_msg,
    const float* __restrict__ W_gcn, const float* __restrict__ b_gcn,
    float* S, int n_links)
{
    __shared__ float qt[4][CHUNK * QSTRIDE + 4];
    const int tid = threadIdx.x;
    const int wave = tid >> 6;
    const int lane = tid & 63;
    const int m = lane & 15;
    const int qd = lane >> 4;

    const int l0 = (blockIdx.x * 4 + wave) * CHUNK;
    const int l1 = min(l0 + CHUNK, n_links);

    // column-layout biases (col = jt*16 + m)
    float bmsgC[4];
#pragma unroll
    for (int jt = 0; jt < 4; ++jt) bmsgC[jt] = b_msg[jt * 16 + m];

    // ---- Phase 1: Q-tile (split-bf16 A and B for accuracy) ----
    {
        bf16x8 WbH[2][4], WbL[2][4];
#pragma unroll
        for (int ks = 0; ks < 2; ++ks)
#pragma unroll
            for (int jt = 0; jt < 4; ++jt) {
                const int nn = jt * 16 + m;
#pragma unroll
                for (int i = 0; i < 8; ++i) {
                    const int kk = 64 + ks * 32 + qd * 8 + i;   // bottom half of W_msg
                    const float w = W_msg[kk * 64 + nn];
                    const short hi = f2bf_rtne(w);
                    WbH[ks][jt][i] = hi;
                    WbL[ks][jt][i] = f2bf_rtne(w - bf2f(hi));
                }
            }
        const int l = l0 + m;
        const bool lv = (l < n_links);
        float xv[16];
        if (lv) {
            const float4* Sr = (const float4*)(state + (size_t)l * D);
            *(float4*)&xv[0]  = Sr[qd * 2];
            *(float4*)&xv[4]  = Sr[qd * 2 + 1];
            *(float4*)&xv[8]  = Sr[8 + qd * 2];
            *(float4*)&xv[12] = Sr[9 + qd * 2];
        } else {
#pragma unroll
            for (int i = 0; i < 16; ++i) xv[i] = 0.0f;
        }
        bf16x8 Ah[2], Al[2];
        split_pack8(&xv[0], &Ah[0], &Al[0]);
        split_pack8(&xv[8], &Ah[1], &Al[1]);
        f32x4 accQ[4];
#pragma unroll
        for (int jt = 0; jt < 4; ++jt) {
            accQ[jt] = (f32x4){0.f, 0.f, 0.f, 0.f};
#pragma unroll
            for (int ks = 0; ks < 2; ++ks) {
                accQ[jt] = __builtin_amdgcn_mfma_f32_16x16x32_bf16(Ah[ks], WbH[ks][jt], accQ[jt], 0, 0, 0);
                accQ[jt] = __builtin_amdgcn_mfma_f32_16x16x32_bf16(Ah[ks], WbL[ks][jt], accQ[jt], 0, 0, 0);
                accQ[jt] = __builtin_amdgcn_mfma_f32_16x16x32_bf16(Al[ks], WbH[ks][jt], accQ[jt], 0, 0, 0);
            }
        }
        // C-layout -> LDS rows (link-in-chunk = qd*4+r, col = jt*16+m), +b_msg
#pragma unroll
        for (int r = 0; r < 4; ++r)
#pragma unroll
            for (int jt = 0; jt < 4; ++jt)
                qt[wave][(qd * 4 + r) * QSTRIDE + jt * 16 + m] = accQ[jt][r] + bmsgC[jt];
    }

    // ---- W_gcn B-frags (split hi/lo) + biases ----
    bf16x8 Gh[2][4], Gl[2][4];
#pragma unroll
    for (int ks = 0; ks < 2; ++ks)
#pragma unroll
        for (int jt = 0; jt < 4; ++jt) {
            const int nn = jt * 16 + m;
#pragma unroll
            for (int i = 0; i < 8; ++i) {
                const int kk = ks * 32 + qd * 8 + i;
                const float w = W_gcn[kk * 64 + nn];
                const short hi = f2bf_rtne(w);
                Gh[ks][jt][i] = hi;
                Gl[ks][jt][i] = f2bf_rtne(w - bf2f(hi));
            }
        }
    float bias_gcn[4], rb[4];
#pragma unroll
    for (int jt = 0; jt < 4; ++jt) {
        bias_gcn[jt] = b_gcn[jt * 16 + m];
        rb[jt] = fmaxf(bias_gcn[jt], 0.0f);
    }

    // ---- Phase 2: per-link edge processing ----
    for (int l = l0; l < l1; ++l) {
        const int es = row_ptr[l];
        const int ee = row_ptr[l + 1];
        const int li = l - l0;

        float qb[16];   // Q[l] + b_msg in A-fragment layout
        *(float4*)&qb[0]  = *(float4*)&qt[wave][li * QSTRIDE + qd * 8];
        *(float4*)&qb[4]  = *(float4*)&qt[wave][li * QSTRIDE + qd * 8 + 4];
        *(float4*)&qb[8]  = *(float4*)&qt[wave][li * QSTRIDE + 32 + qd * 8];
        *(float4*)&qb[12] = *(float4*)&qt[wave][li * QSTRIDE + 32 + qd * 8 + 4];

        float rsum[4] = {0.f, 0.f, 0.f, 0.f};
        for (int eo = es; eo < ee; eo += 16) {
            const int e = eo + m;
            const bool ev = (e < ee);
            const int fi = sfirst[min(e, ee - 1)];

            float pv[16], msg[16];
            const float4* Pr = (const float4*)(P + (size_t)fi * D);
            *(float4*)&pv[0]  = Pr[qd * 2];
            *(float4*)&pv[4]  = Pr[qd * 2 + 1];
            *(float4*)&pv[8]  = Pr[8 + qd * 2];
            *(float4*)&pv[12] = Pr[9 + qd * 2];
#pragma unroll
            for (int i = 0; i < 16; ++i)
                msg[i] = ev ? selu_f(pv[i] + qb[i]) : 0.0f;

            bf16x8 Ah[2];       // plain bf16 A (RTNE)
            Ah[0] = pack8(&msg[0]);
            Ah[1] = pack8(&msg[8]);

            f32x4 acc[4];
#pragma unroll
            for (int jt = 0; jt < 4; ++jt) {
                const float b = bias_gcn[jt];
                acc[jt] = (f32x4){b, b, b, b};
#pragma unroll
                for (int ks = 0; ks < 2; ++ks) {
                    acc[jt] = __builtin_amdgcn_mfma_f32_16x16x32_bf16(Ah[ks], Gh[ks][jt], acc[jt], 0, 0, 0);
                    acc[jt] = __builtin_amdgcn_mfma_f32_16x16x32_bf16(Ah[ks], Gl[ks][jt], acc[jt], 0, 0, 0);
                }
            }

            // relu + accumulate; invalid rows contribute exactly relu(b_gcn)
#pragma unroll
            for (int jt = 0; jt < 4; ++jt)
#pragma unroll
                for (int r = 0; r < 4; ++r)
                    rsum[jt] += fmaxf(acc[jt][r], 0.0f);

            const int over = eo + qd * 4 + 4 - ee;
            const float cnt = (float)max(0, min(4, over));
#pragma unroll
            for (int jt = 0; jt < 4; ++jt)
                rsum[jt] -= rb[jt] * cnt;
        }

#pragma unroll
        for (int jt = 0; jt < 4; ++jt) {
            rsum[jt] += __shfl_xor(rsum[jt], 16, 64);
            rsum[jt] += __shfl_xor(rsum[jt], 32, 64);
        }
        const float outv = (qd == 0) ? rsum[0] : (qd == 1) ? rsum[1]
                         : (qd == 2) ? rsum[2] : rsum[3];
        S[(size_t)l * D + qd * 16 + m] = outv;
    }
}

// ---------------- fused readout: gsum + r1 + r2 + r3, one block per graph ----
__global__ __launch_bounds__(256) void readout_kernel(
    const float* __restrict__ S, const int* __restrict__ grow,
    const float* __restrict__ W_r1, const float* __restrict__ b_r1,
    const float* __restrict__ W_r2, const float* __restrict__ b_r2,
    const float* __restrict__ W_r3, const float* __restrict__ b_r3,
    float* __restrict__ out)
{
    __shared__ float red[4][64];
    __shared__ float gl[64];
    __shared__ float row1[RU];
    __shared__ float row2[RU];
    __shared__ float fin[4];
    const int g = blockIdx.x;
    const int tid = threadIdx.x;
    const int slot = tid >> 6;
    const int lane = tid & 63;

    const int ls = grow[g], le = grow[g + 1];
    float acc = 0.0f;
    for (int l = ls + slot; l < le; l += 4)
        acc += S[(size_t)l * D + lane];
    red[slot][lane] = acc;
    __syncthreads();
    if (slot == 0)
        gl[lane] = red[0][lane] + red[1][lane] + red[2][lane] + red[3][lane];
    __syncthreads();

    float a1 = b_r1[tid];
#pragma unroll 8
    for (int k = 0; k < 64; ++k) a1 += gl[k] * W_r1[k * RU + tid];
    row1[tid] = selu_f(a1);
    __syncthreads();

    float a2 = b_r2[tid];
#pragma unroll 8
    for (int k = 0; k < RU; ++k) a2 += row1[k] * W_r2[k * RU + tid];
    row2[tid] = selu_f(a2);
    __syncthreads();

    float p = row2[tid] * W_r3[tid];
#pragma unroll
    for (int off = 32; off >= 1; off >>= 1)
        p += __shfl_down(p, off, 64);
    if (lane == 0) fin[slot] = p;
    __syncthreads();
    if (tid == 0)
        out[g] = fin[0] + fin[1] + fin[2] + fin[3] + b_r3[0];
}

extern "C" void kernel_launch(void* const* d_in, const int* in_sizes, int n_in,
                              void* d_out, int out_size, void* d_ws, size_t ws_size,
                              hipStream_t stream)
{
    const float* states_action = (const float*)d_in[0];
    const float* W_msg = (const float*)d_in[1];
    const float* b_msg = (const float*)d_in[2];
    const float* W_gcn = (const float*)d_in[3];
    const float* b_gcn = (const float*)d_in[4];
    const float* W_r1 = (const float*)d_in[5];
    const float* b_r1 = (const float*)d_in[6];
    const float* W_r2 = (const float*)d_in[7];
    const float* b_r2 = (const float*)d_in[8];
    const float* W_r3 = (const float*)d_in[9];
    const float* b_r3 = (const float*)d_in[10];
    const int* gid = (const int*)d_in[11];
    const int* first = (const int*)d_in[12];
    const int* second = (const int*)d_in[13];

    const int n_links = in_sizes[0] / D;     // 100000
    const int n_edges = in_sizes[12];        // 1600000
    const int G = out_size;                  // 256

    const size_t state_bytes = (size_t)n_links * D * sizeof(float);
    char* ws = (char*)d_ws;
    float* S = (float*)ws;                               // 25.6 MB
    float* P = (float*)(ws + state_bytes);               // 25.6 MB
    char* ws2 = ws + 2 * state_bytes;
    int* counts = (int*)ws2;             ws2 += (size_t)(n_links + 1) * sizeof(int);
    int* row_ptr = (int*)ws2;            ws2 += (size_t)(n_links + 1) * sizeof(int);
    int* cursor = (int*)ws2;             ws2 += (size_t)(n_links + 1) * sizeof(int);
    int* gcounts = (int*)ws2;            ws2 += (size_t)(G + 1) * sizeof(int);
    int* grow = (int*)ws2;               ws2 += (size_t)(G + 1) * sizeof(int);
    int* gcur = (int*)ws2;               ws2 += (size_t)(G + 1) * sizeof(int);
    int* sfirst = (int*)ws2;             ws2 += (size_t)n_edges * sizeof(int);

    // ---- CSR setup (rebuilt every launch; ws is poisoned between runs) ----
    hipMemsetAsync(counts, 0, (size_t)(n_links + 1) * sizeof(int), stream);
    hipMemsetAsync(gcounts, 0, (size_t)(G + 1) * sizeof(int), stream);
    hist_kernel<<<512, 256, 0, stream>>>(second, counts, n_edges);
    hist_kernel<<<512, 256, 0, stream>>>(gid, gcounts, n_links);
    scan_kernel<<<1, 1024, 0, stream>>>(counts, row_ptr, cursor, n_links);
    scan_kernel<<<1, 1024, 0, stream>>>(gcounts, grow, gcur, G);
    scatter_kernel<<<512, 256, 0, stream>>>(first, second, cursor, sfirst, n_edges);

    // ---- T = 4 message-passing iterations ----
    const int edge_blocks = (n_links + 4 * CHUNK - 1) / (4 * CHUNK);  // 1563
    const float* state_in = states_action;
    for (int t = 0; t < 4; ++t) {
        p_mfma_kernel<<<782, 256, 0, stream>>>(state_in, W_msg, P, n_links);
        edge_link_kernel<<<edge_blocks, 256, 0, stream>>>(state_in, P, sfirst, row_ptr,
                                                          b_msg, W_msg, W_gcn, b_gcn,
                                                          S, n_links);
        state_in = S;
    }

    // ---- fused readout ----
    readout_kernel<<<G, 256, 0, stream>>>(S, grow, W_r1, b_r1, W_r2, b_r2,
                                          W_r3, b_r3, (float*)d_out);
}

// Round 7
// 1376.217 us; speedup vs baseline: 1.0900x; 1.0900x over previous
//
#include <hip/hip_runtime.h>
#include <hip/hip_bf16.h>
#include <math.h>

#define D 64
#define RU 256
#define CHUNK 8
#define QSTRIDE 68

typedef short bf16x8 __attribute__((ext_vector_type(8)));
typedef float f32x4 __attribute__((ext_vector_type(4)));

__device__ __forceinline__ float selu_f(float x) {
    return x > 0.0f ? 1.0507009873554805f * x
                    : 1.7580993408473766f * (__expf(x) - 1.0f);
}

__device__ __forceinline__ short f2bf_rtne(float x) {
    union { float f; unsigned u; } v; v.f = x;
    unsigned r = (v.u + 0x7FFFu + ((v.u >> 16) & 1u)) >> 16;
    return (short)r;
}
__device__ __forceinline__ float bf2f(short s) {
    union { float f; unsigned u; } v; v.u = ((unsigned)(unsigned short)s) << 16;
    return v.f;
}

__device__ __forceinline__ bf16x8 pack8(const float* v) {
    union { bf16x8 v; unsigned u[4]; } H;
#pragma unroll
    for (int j = 0; j < 4; ++j) {
        float2 p; p.x = v[2 * j]; p.y = v[2 * j + 1];
        __hip_bfloat162 hb = __float22bfloat162_rn(p);
        H.u[j] = *(unsigned*)&hb;
    }
    return H.v;
}

__device__ __forceinline__ void split_pack8(const float* v, bf16x8* hi, bf16x8* lo) {
    union { bf16x8 v; unsigned u[4]; } H, L;
#pragma unroll
    for (int j = 0; j < 4; ++j) {
        float2 p; p.x = v[2 * j]; p.y = v[2 * j + 1];
        __hip_bfloat162 hb = __float22bfloat162_rn(p);
        unsigned hu = *(unsigned*)&hb;
        H.u[j] = hu;
        union { unsigned u; float f; } e, o;
        e.u = hu << 16;
        o.u = hu & 0xffff0000u;
        float2 q; q.x = p.x - e.f; q.y = p.y - o.f;
        __hip_bfloat162 lb = __float22bfloat162_rn(q);
        L.u[j] = *(unsigned*)&lb;
    }
    *hi = H.v; *lo = L.v;
}

// ---------------- CSR setup (once per launch) ----------------

__global__ __launch_bounds__(256) void hist_kernel(
    const int* __restrict__ keys, int* __restrict__ counts, int n)
{
    for (int e = blockIdx.x * blockDim.x + threadIdx.x; e < n;
         e += gridDim.x * blockDim.x)
        atomicAdd(&counts[keys[e]], 1);
}

__global__ __launch_bounds__(1024) void scan_kernel(
    const int* __restrict__ counts, int* __restrict__ row_ptr,
    int* __restrict__ cursor, int n)
{
    __shared__ int wsum[16];
    __shared__ int woff[16];
    __shared__ int s_total;
    __shared__ int s_carry;
    const int tid = threadIdx.x, wave = tid >> 6, lane = tid & 63;
    if (tid == 0) s_carry = 0;
    __syncthreads();
    for (int base = 0; base < n; base += 1024) {
        const int i = base + tid;
        const int x = (i < n) ? counts[i] : 0;
        int v = x;
#pragma unroll
        for (int off = 1; off < 64; off <<= 1) {
            int t = __shfl_up(v, off, 64);
            if (lane >= off) v += t;
        }
        if (lane == 63) wsum[wave] = v;
        __syncthreads();
        if (wave == 0) {
            int s = (lane < 16) ? wsum[lane] : 0;
#pragma unroll
            for (int off = 1; off < 16; off <<= 1) {
                int t = __shfl_up(s, off, 64);
                if (lane >= off) s += t;
            }
            if (lane < 16) woff[lane] = s - wsum[lane];
            if (lane == 15) s_total = s;
        }
        __syncthreads();
        const int carry = s_carry;
        const int excl = carry + woff[wave] + (v - x);
        if (i < n) { row_ptr[i] = excl; cursor[i] = excl; }
        __syncthreads();
        if (tid == 0) s_carry += s_total;
        __syncthreads();
    }
    if (tid == 0) row_ptr[n] = s_carry;
}

__global__ __launch_bounds__(256) void scatter_kernel(
    const int* __restrict__ first, const int* __restrict__ second,
    int* __restrict__ cursor, int* __restrict__ sfirst, int n_edges)
{
    for (int e = blockIdx.x * blockDim.x + threadIdx.x; e < n_edges;
         e += gridDim.x * blockDim.x) {
        const int pos = atomicAdd(&cursor[second[e]], 1);
        sfirst[pos] = first[e];
    }
}

// ---------------- P via MFMA (split-bf16 compute, bf16 output) ----------------
// P = bf16(state @ W_msg[0:64,:])
__global__ __launch_bounds__(256) void p_mfma_kernel(
    const float* __restrict__ state, const float* __restrict__ W_msg,
    unsigned short* __restrict__ P, int n_links)
{
    const int tid = threadIdx.x;
    const int wave = tid >> 6;
    const int lane = tid & 63;
    const int m = lane & 15;
    const int qd = lane >> 4;

    bf16x8 Bh[2][4], Bl[2][4];
#pragma unroll
    for (int ks = 0; ks < 2; ++ks)
#pragma unroll
        for (int jt = 0; jt < 4; ++jt) {
            const int nn = jt * 16 + m;
#pragma unroll
            for (int i = 0; i < 8; ++i) {
                const int kk = ks * 32 + qd * 8 + i;
                const float w = W_msg[kk * 64 + nn];
                const short hi = f2bf_rtne(w);
                Bh[ks][jt][i] = hi;
                Bl[ks][jt][i] = f2bf_rtne(w - bf2f(hi));
            }
        }

    const int ngroups = (n_links + 63) >> 6;
    for (int g = blockIdx.x; g < ngroups; g += gridDim.x) {
        const int base = g * 64 + wave * 16;
        const int l = base + m;
        const bool lv = (l < n_links);
        float xv[16];
        if (lv) {
            const float4* Sr = (const float4*)(state + (size_t)l * D);
            *(float4*)&xv[0]  = Sr[qd * 2];
            *(float4*)&xv[4]  = Sr[qd * 2 + 1];
            *(float4*)&xv[8]  = Sr[8 + qd * 2];
            *(float4*)&xv[12] = Sr[9 + qd * 2];
        } else {
#pragma unroll
            for (int i = 0; i < 16; ++i) xv[i] = 0.0f;
        }
        bf16x8 Ah[2], Al[2];
        split_pack8(&xv[0], &Ah[0], &Al[0]);
        split_pack8(&xv[8], &Ah[1], &Al[1]);
        f32x4 accP[4];
#pragma unroll
        for (int jt = 0; jt < 4; ++jt) {
            accP[jt] = (f32x4){0.f, 0.f, 0.f, 0.f};
#pragma unroll
            for (int ks = 0; ks < 2; ++ks) {
                accP[jt] = __builtin_amdgcn_mfma_f32_16x16x32_bf16(Ah[ks], Bh[ks][jt], accP[jt], 0, 0, 0);
                accP[jt] = __builtin_amdgcn_mfma_f32_16x16x32_bf16(Ah[ks], Bl[ks][jt], accP[jt], 0, 0, 0);
                accP[jt] = __builtin_amdgcn_mfma_f32_16x16x32_bf16(Al[ks], Bh[ks][jt], accP[jt], 0, 0, 0);
            }
        }
#pragma unroll
        for (int r = 0; r < 4; ++r) {
            const int lr = base + qd * 4 + r;
            if (lr < n_links) {
#pragma unroll
                for (int jt = 0; jt < 4; ++jt)
                    P[(size_t)lr * D + jt * 16 + m] =
                        (unsigned short)f2bf_rtne(accP[jt][r]);
            }
        }
    }
}

// ---------------- link-centric fused edge kernel, software-pipelined --------
// Wave owns CHUNK=8 consecutive links. Phase 1: Q-tile = state-chunk @
// W_msg_bot + b_msg (split-MFMA), stashed in LDS (C->A layout transform).
// Phase 2: 2-stage pipeline over the wave's (link, tile) sequence — next
// tile's sfirst + bf16-P row loads issue before current tile's compute.
__global__ __launch_bounds__(256) void edge_link_kernel(
    const float* state, const unsigned short* __restrict__ P,
    const int* __restrict__ sfirst, const int* __restrict__ row_ptr,
    const float* __restrict__ b_msg, const float* __restrict__ W_msg,
    const float* __restrict__ W_gcn, const float* __restrict__ b_gcn,
    float* S, int n_links)
{
    __shared__ float qt[4][CHUNK * QSTRIDE + 4];
    const int tid = threadIdx.x;
    const int wave = tid >> 6;
    const int lane = tid & 63;
    const int m = lane & 15;
    const int qd = lane >> 4;

    const int l0 = (blockIdx.x * 4 + wave) * CHUNK;
    const int l1 = min(l0 + CHUNK, n_links);

    float bmsgC[4];
#pragma unroll
    for (int jt = 0; jt < 4; ++jt) bmsgC[jt] = b_msg[jt * 16 + m];

    // ---- Phase 1: Q-tile (split-bf16, fp32-equivalent) ----
    {
        bf16x8 WbH[2][4], WbL[2][4];
#pragma unroll
        for (int ks = 0; ks < 2; ++ks)
#pragma unroll
            for (int jt = 0; jt < 4; ++jt) {
                const int nn = jt * 16 + m;
#pragma unroll
                for (int i = 0; i < 8; ++i) {
                    const int kk = 64 + ks * 32 + qd * 8 + i;
                    const float w = W_msg[kk * 64 + nn];
                    const short hi = f2bf_rtne(w);
                    WbH[ks][jt][i] = hi;
                    WbL[ks][jt][i] = f2bf_rtne(w - bf2f(hi));
                }
            }
        const int l = l0 + m;
        const bool lv = (l < n_links) && (m < CHUNK);
        float xv[16];
        if (lv) {
            const float4* Sr = (const float4*)(state + (size_t)l * D);
            *(float4*)&xv[0]  = Sr[qd * 2];
            *(float4*)&xv[4]  = Sr[qd * 2 + 1];
            *(float4*)&xv[8]  = Sr[8 + qd * 2];
            *(float4*)&xv[12] = Sr[9 + qd * 2];
        } else {
#pragma unroll
            for (int i = 0; i < 16; ++i) xv[i] = 0.0f;
        }
        bf16x8 Ah[2], Al[2];
        split_pack8(&xv[0], &Ah[0], &Al[0]);
        split_pack8(&xv[8], &Ah[1], &Al[1]);
        f32x4 accQ[4];
#pragma unroll
        for (int jt = 0; jt < 4; ++jt) {
            accQ[jt] = (f32x4){0.f, 0.f, 0.f, 0.f};
#pragma unroll
            for (int ks = 0; ks < 2; ++ks) {
                accQ[jt] = __builtin_amdgcn_mfma_f32_16x16x32_bf16(Ah[ks], WbH[ks][jt], accQ[jt], 0, 0, 0);
                accQ[jt] = __builtin_amdgcn_mfma_f32_16x16x32_bf16(Ah[ks], WbL[ks][jt], accQ[jt], 0, 0, 0);
                accQ[jt] = __builtin_amdgcn_mfma_f32_16x16x32_bf16(Al[ks], WbH[ks][jt], accQ[jt], 0, 0, 0);
            }
        }
#pragma unroll
        for (int r = 0; r < 4; ++r) {
            const int row = qd * 4 + r;
            if (row < CHUNK) {
#pragma unroll
                for (int jt = 0; jt < 4; ++jt)
                    qt[wave][row * QSTRIDE + jt * 16 + m] = accQ[jt][r] + bmsgC[jt];
            }
        }
    }

    // ---- W_gcn B-frags (split hi/lo) + biases ----
    bf16x8 Gh[2][4], Gl[2][4];
#pragma unroll
    for (int ks = 0; ks < 2; ++ks)
#pragma unroll
        for (int jt = 0; jt < 4; ++jt) {
            const int nn = jt * 16 + m;
#pragma unroll
            for (int i = 0; i < 8; ++i) {
                const int kk = ks * 32 + qd * 8 + i;
                const float w = W_gcn[kk * 64 + nn];
                const short hi = f2bf_rtne(w);
                Gh[ks][jt][i] = hi;
                Gl[ks][jt][i] = f2bf_rtne(w - bf2f(hi));
            }
        }
    float bias_gcn[4], rb[4];
#pragma unroll
    for (int jt = 0; jt < 4; ++jt) {
        bias_gcn[jt] = b_gcn[jt * 16 + m];
        rb[jt] = fmaxf(bias_gcn[jt], 0.0f);
    }

    // ---- Phase 2: pipelined tile loop over this wave's (link, tile) seq ----
    if (l0 >= n_links) return;

    int l = l0;
    int eo = row_ptr[l];
    int ee = row_ptr[l + 1];
    // emit zero rows for leading empty links
    while (l < l1 && ee == eo) {
        S[(size_t)l * D + qd * 16 + m] = 0.0f;
        ++l;
        if (l < l1) ee = row_ptr[l + 1];
    }
    if (l < l1) {
        // prefetch first tile
        int fi = sfirst[min(eo + m, ee - 1)];
        const unsigned short* Pr = P + (size_t)fi * D;
        bf16x8 pr0 = *(const bf16x8*)(Pr + qd * 8);
        bf16x8 pr1 = *(const bf16x8*)(Pr + 32 + qd * 8);

        float rsum[4] = {0.f, 0.f, 0.f, 0.f};
        while (true) {
            const bf16x8 c0 = pr0, c1 = pr1;

            // compute next state; emit zeros for empty links on the way
            int nl = l, neo = eo + 16, nee = ee;
            bool have_next = true;
            if (neo >= ee) {
                nl = l + 1;
                neo = ee;                       // row_ptr[nl] == ee (contiguous)
                while (nl < l1) {
                    nee = row_ptr[nl + 1];
                    if (nee > neo) break;
                    S[(size_t)nl * D + qd * 16 + m] = 0.0f;
                    ++nl;
                }
                if (nl >= l1) have_next = false;
            }
            // prefetch next tile
            if (have_next) {
                const int fin_ = sfirst[min(neo + m, nee - 1)];
                const unsigned short* Prn = P + (size_t)fin_ * D;
                pr0 = *(const bf16x8*)(Prn + qd * 8);
                pr1 = *(const bf16x8*)(Prn + 32 + qd * 8);
            }

            // ---- compute current tile (l, eo, ee) ----
            const int li = l - l0;
            float qb[16];
            *(float4*)&qb[0]  = *(float4*)&qt[wave][li * QSTRIDE + qd * 8];
            *(float4*)&qb[4]  = *(float4*)&qt[wave][li * QSTRIDE + qd * 8 + 4];
            *(float4*)&qb[8]  = *(float4*)&qt[wave][li * QSTRIDE + 32 + qd * 8];
            *(float4*)&qb[12] = *(float4*)&qt[wave][li * QSTRIDE + 32 + qd * 8 + 4];

            const bool ev = (eo + m < ee);
            float msg[16];
#pragma unroll
            for (int i = 0; i < 8; ++i) {
                msg[i]     = ev ? selu_f(bf2f(c0[i]) + qb[i])     : 0.0f;
                msg[8 + i] = ev ? selu_f(bf2f(c1[i]) + qb[8 + i]) : 0.0f;
            }

            bf16x8 Ah[2];
            Ah[0] = pack8(&msg[0]);
            Ah[1] = pack8(&msg[8]);

            f32x4 acc[4];
#pragma unroll
            for (int jt = 0; jt < 4; ++jt) {
                const float b = bias_gcn[jt];
                acc[jt] = (f32x4){b, b, b, b};
#pragma unroll
                for (int ks = 0; ks < 2; ++ks) {
                    acc[jt] = __builtin_amdgcn_mfma_f32_16x16x32_bf16(Ah[ks], Gh[ks][jt], acc[jt], 0, 0, 0);
                    acc[jt] = __builtin_amdgcn_mfma_f32_16x16x32_bf16(Ah[ks], Gl[ks][jt], acc[jt], 0, 0, 0);
                }
            }

#pragma unroll
            for (int jt = 0; jt < 4; ++jt)
#pragma unroll
                for (int r = 0; r < 4; ++r)
                    rsum[jt] += fmaxf(acc[jt][r], 0.0f);

            const int over = eo + qd * 4 + 4 - ee;
            const float cnt = (float)max(0, min(4, over));
#pragma unroll
            for (int jt = 0; jt < 4; ++jt)
                rsum[jt] -= rb[jt] * cnt;

            // link epilogue if this was the last tile of link l
            if (eo + 16 >= ee) {
#pragma unroll
                for (int jt = 0; jt < 4; ++jt) {
                    rsum[jt] += __shfl_xor(rsum[jt], 16, 64);
                    rsum[jt] += __shfl_xor(rsum[jt], 32, 64);
                }
                const float outv = (qd == 0) ? rsum[0] : (qd == 1) ? rsum[1]
                                 : (qd == 2) ? rsum[2] : rsum[3];
                S[(size_t)l * D + qd * 16 + m] = outv;
#pragma unroll
                for (int jt = 0; jt < 4; ++jt) rsum[jt] = 0.0f;
            }

            if (!have_next) break;
            l = nl; eo = neo; ee = nee;
        }
    }
}

// ---------------- fused readout ----------------
__global__ __launch_bounds__(256) void readout_kernel(
    const float* __restrict__ S, const int* __restrict__ grow,
    const float* __restrict__ W_r1, const float* __restrict__ b_r1,
    const float* __restrict__ W_r2, const float* __restrict__ b_r2,
    const float* __restrict__ W_r3, const float* __restrict__ b_r3,
    float* __restrict__ out)
{
    __shared__ float red[4][64];
    __shared__ float gl[64];
    __shared__ float row1[RU];
    __shared__ float row2[RU];
    __shared__ float fin[4];
    const int g = blockIdx.x;
    const int tid = threadIdx.x;
    const int slot = tid >> 6;
    const int lane = tid & 63;

    const int ls = grow[g], le = grow[g + 1];
    float acc = 0.0f;
    for (int l = ls + slot; l < le; l += 4)
        acc += S[(size_t)l * D + lane];
    red[slot][lane] = acc;
    __syncthreads();
    if (slot == 0)
        gl[lane] = red[0][lane] + red[1][lane] + red[2][lane] + red[3][lane];
    __syncthreads();

    float a1 = b_r1[tid];
#pragma unroll 8
    for (int k = 0; k < 64; ++k) a1 += gl[k] * W_r1[k * RU + tid];
    row1[tid] = selu_f(a1);
    __syncthreads();

    float a2 = b_r2[tid];
#pragma unroll 8
    for (int k = 0; k < RU; ++k) a2 += row1[k] * W_r2[k * RU + tid];
    row2[tid] = selu_f(a2);
    __syncthreads();

    float p = row2[tid] * W_r3[tid];
#pragma unroll
    for (int off = 32; off >= 1; off >>= 1)
        p += __shfl_down(p, off, 64);
    if (lane == 0) fin[slot] = p;
    __syncthreads();
    if (tid == 0)
        out[g] = fin[0] + fin[1] + fin[2] + fin[3] + b_r3[0];
}

extern "C" void kernel_launch(void* const* d_in, const int* in_sizes, int n_in,
                              void* d_out, int out_size, void* d_ws, size_t ws_size,
                              hipStream_t stream)
{
    const float* states_action = (const float*)d_in[0];
    const float* W_msg = (const float*)d_in[1];
    const float* b_msg = (const float*)d_in[2];
    const float* W_gcn = (const float*)d_in[3];
    const float* b_gcn = (const float*)d_in[4];
    const float* W_r1 = (const float*)d_in[5];
    const float* b_r1 = (const float*)d_in[6];
    const float* W_r2 = (const float*)d_in[7];
    const float* b_r2 = (const float*)d_in[8];
    const float* W_r3 = (const float*)d_in[9];
    const float* b_r3 = (const float*)d_in[10];
    const int* gid = (const int*)d_in[11];
    const int* first = (const int*)d_in[12];
    const int* second = (const int*)d_in[13];

    const int n_links = in_sizes[0] / D;     // 100000
    const int n_edges = in_sizes[12];        // 1600000
    const int G = out_size;                  // 256

    const size_t state_bytes = (size_t)n_links * D * sizeof(float);
    char* ws = (char*)d_ws;
    float* S = (float*)ws;                               // 25.6 MB
    unsigned short* Pb = (unsigned short*)(ws + state_bytes);   // 12.8 MB
    char* ws2 = ws + state_bytes + (size_t)n_links * D * sizeof(unsigned short);
    int* counts = (int*)ws2;             ws2 += (size_t)(n_links + 1) * sizeof(int);
    int* row_ptr = (int*)ws2;            ws2 += (size_t)(n_links + 1) * sizeof(int);
    int* cursor = (int*)ws2;             ws2 += (size_t)(n_links + 1) * sizeof(int);
    int* gcounts = (int*)ws2;            ws2 += (size_t)(G + 1) * sizeof(int);
    int* grow = (int*)ws2;               ws2 += (size_t)(G + 1) * sizeof(int);
    int* gcur = (int*)ws2;               ws2 += (size_t)(G + 1) * sizeof(int);
    int* sfirst = (int*)ws2;             ws2 += (size_t)n_edges * sizeof(int);

    // ---- CSR setup (rebuilt every launch; ws is poisoned between runs) ----
    hipMemsetAsync(counts, 0, (size_t)(n_links + 1) * sizeof(int), stream);
    hipMemsetAsync(gcounts, 0, (size_t)(G + 1) * sizeof(int), stream);
    hist_kernel<<<512, 256, 0, stream>>>(second, counts, n_edges);
    hist_kernel<<<512, 256, 0, stream>>>(gid, gcounts, n_links);
    scan_kernel<<<1, 1024, 0, stream>>>(counts, row_ptr, cursor, n_links);
    scan_kernel<<<1, 1024, 0, stream>>>(gcounts, grow, gcur, G);
    scatter_kernel<<<512, 256, 0, stream>>>(first, second, cursor, sfirst, n_edges);

    // ---- T = 4 message-passing iterations ----
    const int edge_blocks = (n_links + 4 * CHUNK - 1) / (4 * CHUNK);  // 3125
    const float* state_in = states_action;
    for (int t = 0; t < 4; ++t) {
        p_mfma_kernel<<<782, 256, 0, stream>>>(state_in, W_msg, Pb, n_links);
        edge_link_kernel<<<edge_blocks, 256, 0, stream>>>(state_in, Pb, sfirst, row_ptr,
                                                          b_msg, W_msg, W_gcn, b_gcn,
                                                          S, n_links);
        state_in = S;
    }

    // ---- fused readout ----
    readout_kernel<<<G, 256, 0, stream>>>(S, grow, W_r1, b_r1, W_r2, b_r2,
                                          W_r3, b_r3, (float*)d_out);
}